// Round 1
// baseline (57.574 us; speedup 1.0000x reference)
//
#include <hip/hip_runtime.h>
#include <hip/hip_bf16.h>

#define S_DIM 2048
#define B_DIM 32
#define E_DIM 1024
#define H_DIM 1024

// h-chunks for v_enc/v_dec two-stage reduce
#define VCHUNKS 32           // 32 chunks of 32 rows each
// k3 decomposition: each wave handles CH s-rows; 64 wave-chunks per batch b
#define CH 32
#define CPB (S_DIM / CH)     // 64 chunks per b
#define NWAVES (B_DIM * CPB) // 2048 waves total

// ---------------- workspace layout (floats) ----------------
// penc  [VCHUNKS][E]      offset 0          (32768)
// pdec  [VCHUNKS][H]      offset 32768      (32768)
// venc  [E]               offset 65536      (1024)
// vdec  [H]               offset 66560      (1024)
// expw  [B][S]            offset 67584      (65536)
// pl    [NWAVES]          offset 133120     (2048)
// pctx  [NWAVES][E]       offset 135168     (2097152)
// total: 2232320 floats = ~8.93 MB

__global__ __launch_bounds__(256) void k1_partial_v(
    const float* __restrict__ W_enc, const float* __restrict__ W_dec,
    const float* __restrict__ w_score, float* __restrict__ penc,
    float* __restrict__ pdec) {
  int bid = blockIdx.x;           // 0..255 (128 enc, 128 dec)
  int t = threadIdx.x;
  bool enc = bid < 128;
  int idx = enc ? bid : bid - 128;
  int hc = idx >> 2;              // 0..31 h-chunk
  int e0 = (idx & 3) << 8;        // 0,256,512,768
  const float* M = enc ? W_enc : W_dec;
  int h0 = hc * 32;
  float acc = 0.f;
#pragma unroll 8
  for (int r = 0; r < 32; ++r) {
    float w = w_score[h0 + r];
    acc = fmaf(w, M[(size_t)(h0 + r) * E_DIM + e0 + t], acc);
  }
  float* dst = enc ? penc : pdec;
  dst[hc * E_DIM + e0 + t] = acc;
}

__global__ __launch_bounds__(256) void k2_finalize_v(
    const float* __restrict__ penc, const float* __restrict__ pdec,
    float* __restrict__ venc, float* __restrict__ vdec) {
  int g = blockIdx.x * 256 + threadIdx.x;  // 0..2047
  bool enc = g < E_DIM;
  const float* p = enc ? penc : pdec;
  int e = enc ? g : g - E_DIM;
  float acc = 0.f;
#pragma unroll 8
  for (int c = 0; c < VCHUNKS; ++c) acc += p[c * E_DIM + e];
  (enc ? venc : vdec)[e] = acc;
}

__device__ __forceinline__ float wave_allreduce_sum(float v) {
#pragma unroll
  for (int off = 1; off < 64; off <<= 1) v += __shfl_xor(v, off, 64);
  return v;
}

// Main streaming pass: scores + exp + fused partial weighted-context.
__global__ __launch_bounds__(256) void k3_stream(
    const float* __restrict__ h_enc, const float* __restrict__ h_t,
    const float* __restrict__ venc, const float* __restrict__ vdec,
    float* __restrict__ expw, float* __restrict__ pl,
    float* __restrict__ pctx) {
  int wid = (blockIdx.x * blockDim.x + threadIdx.x) >> 6;  // 0..2047
  int lane = threadIdx.x & 63;
  int b = wid >> 6;       // 64 chunks per b
  int ci = wid & 63;
  int s0 = ci * CH;
  int e_base = lane * 4;  // lane covers e = lane*4 + k*256, k=0..3

  float4 ve[4];
#pragma unroll
  for (int k = 0; k < 4; ++k)
    ve[k] = *reinterpret_cast<const float4*>(venc + e_base + k * 256);

  // c_b = vdec . h_t[b]
  float cb = 0.f;
#pragma unroll
  for (int k = 0; k < 4; ++k) {
    float4 vd = *reinterpret_cast<const float4*>(vdec + e_base + k * 256);
    float4 ht = *reinterpret_cast<const float4*>(h_t + b * H_DIM + e_base + k * 256);
    cb = fmaf(vd.x, ht.x, cb);
    cb = fmaf(vd.y, ht.y, cb);
    cb = fmaf(vd.z, ht.z, cb);
    cb = fmaf(vd.w, ht.w, cb);
  }
  cb = wave_allreduce_sum(cb);

  float4 ctx0 = {0.f, 0.f, 0.f, 0.f};
  float4 ctx1 = {0.f, 0.f, 0.f, 0.f};
  float4 ctx2 = {0.f, 0.f, 0.f, 0.f};
  float4 ctx3 = {0.f, 0.f, 0.f, 0.f};
  float lsum = 0.f;

  for (int s = s0; s < s0 + CH; ++s) {
    const float* row = h_enc + ((size_t)s * B_DIM + b) * E_DIM + e_base;
    float4 a0 = *reinterpret_cast<const float4*>(row);
    float4 a1 = *reinterpret_cast<const float4*>(row + 256);
    float4 a2 = *reinterpret_cast<const float4*>(row + 512);
    float4 a3 = *reinterpret_cast<const float4*>(row + 768);

    float d = 0.f;
    d = fmaf(a0.x, ve[0].x, d); d = fmaf(a0.y, ve[0].y, d);
    d = fmaf(a0.z, ve[0].z, d); d = fmaf(a0.w, ve[0].w, d);
    d = fmaf(a1.x, ve[1].x, d); d = fmaf(a1.y, ve[1].y, d);
    d = fmaf(a1.z, ve[1].z, d); d = fmaf(a1.w, ve[1].w, d);
    d = fmaf(a2.x, ve[2].x, d); d = fmaf(a2.y, ve[2].y, d);
    d = fmaf(a2.z, ve[2].z, d); d = fmaf(a2.w, ve[2].w, d);
    d = fmaf(a3.x, ve[3].x, d); d = fmaf(a3.y, ve[3].y, d);
    d = fmaf(a3.z, ve[3].w * 0.f + ve[3].z, d); d = fmaf(a3.w, ve[3].w, d);

    d = wave_allreduce_sum(d);
    float sc = tanhf(d + cb);
    float w = __expf(sc);   // no max-subtract needed: sc in [-1,1]
    if (lane == 0) expw[b * S_DIM + s] = w;
    lsum += w;

    ctx0.x = fmaf(w, a0.x, ctx0.x); ctx0.y = fmaf(w, a0.y, ctx0.y);
    ctx0.z = fmaf(w, a0.z, ctx0.z); ctx0.w = fmaf(w, a0.w, ctx0.w);
    ctx1.x = fmaf(w, a1.x, ctx1.x); ctx1.y = fmaf(w, a1.y, ctx1.y);
    ctx1.z = fmaf(w, a1.z, ctx1.z); ctx1.w = fmaf(w, a1.w, ctx1.w);
    ctx2.x = fmaf(w, a2.x, ctx2.x); ctx2.y = fmaf(w, a2.y, ctx2.y);
    ctx2.z = fmaf(w, a2.z, ctx2.z); ctx2.w = fmaf(w, a2.w, ctx2.w);
    ctx3.x = fmaf(w, a3.x, ctx3.x); ctx3.y = fmaf(w, a3.y, ctx3.y);
    ctx3.z = fmaf(w, a3.z, ctx3.z); ctx3.w = fmaf(w, a3.w, ctx3.w);
  }

  float* pc = pctx + (size_t)wid * E_DIM + e_base;
  *reinterpret_cast<float4*>(pc)       = ctx0;
  *reinterpret_cast<float4*>(pc + 256) = ctx1;
  *reinterpret_cast<float4*>(pc + 512) = ctx2;
  *reinterpret_cast<float4*>(pc + 768) = ctx3;
  if (lane == 0) pl[wid] = lsum;
}

// Final reduce: context = sum(pctx)/l_b ; alphas = expw/l_b
__global__ __launch_bounds__(256) void k4_finalize(
    const float* __restrict__ pl, const float* __restrict__ pctx,
    const float* __restrict__ expw, float* __restrict__ out) {
  int bid = blockIdx.x;  // 0..511 : [0,256) ctx, [256,512) alphas
  int t = threadIdx.x;
  int lane = t & 63;
  bool isCtx = bid < 256;
  int idx = isCtx ? bid : bid - 256;
  int b = idx >> 3;

  __shared__ float s_l;
  __shared__ float s_half[128];

  if (t < 64) {
    float v = pl[b * CPB + lane];
    v = wave_allreduce_sum(v);
    if (lane == 0) s_l = v;
  }
  __syncthreads();
  float lb = s_l;

  if (isCtx) {
    int e0 = (idx & 7) * 128;
    int eo = t & 127;
    int c0 = (t >> 7) * 32;  // two halves of the 64 chunks
    const float* base = pctx + (size_t)(b * CPB + c0) * E_DIM + e0 + eo;
    float acc = 0.f;
#pragma unroll 8
    for (int c = 0; c < 32; ++c) acc += base[(size_t)c * E_DIM];
    if (t >= 128) s_half[eo] = acc;
    __syncthreads();
    if (t < 128) out[b * E_DIM + e0 + eo] = (acc + s_half[eo]) / lb;
  } else {
    int sb = (idx & 7) * 256;
    int o = b * S_DIM + sb + t;
    out[B_DIM * E_DIM + o] = expw[o] / lb;
  }
}

extern "C" void kernel_launch(void* const* d_in, const int* in_sizes, int n_in,
                              void* d_out, int out_size, void* d_ws, size_t ws_size,
                              hipStream_t stream) {
  const float* h_t     = (const float*)d_in[0];
  const float* h_enc   = (const float*)d_in[1];
  const float* W_enc   = (const float*)d_in[2];
  const float* W_dec   = (const float*)d_in[3];
  const float* w_score = (const float*)d_in[4];
  float* out = (float*)d_out;
  float* ws = (float*)d_ws;

  float* penc = ws;                  // 32768
  float* pdec = penc + 32768;        // 32768
  float* venc = pdec + 32768;        // 1024
  float* vdec = venc + 1024;         // 1024
  float* expw = vdec + 1024;         // 65536
  float* pl   = expw + 65536;        // 2048
  float* pctx = pl + 2048;           // 2097152

  hipLaunchKernelGGL(k1_partial_v, dim3(256), dim3(256), 0, stream,
                     W_enc, W_dec, w_score, penc, pdec);
  hipLaunchKernelGGL(k2_finalize_v, dim3(8), dim3(256), 0, stream,
                     penc, pdec, venc, vdec);
  hipLaunchKernelGGL(k3_stream, dim3(NWAVES * 64 / 256), dim3(256), 0, stream,
                     h_enc, h_t, venc, vdec, expw, pl, pctx);
  hipLaunchKernelGGL(k4_finalize, dim3(512), dim3(256), 0, stream,
                     pl, pctx, expw, out);
}